// Round 1
// baseline (5448.655 us; speedup 1.0000x reference)
//
#include <hip/hip_runtime.h>
#include <hip/hip_bf16.h>

// GPT-2 small forward on gfx950. bf16 MFMA GEMMs (f32 accum), flash attention.
// Weight bf16 transposes are staged in d_out (dead before lm_head overwrites it);
// activations live in d_ws (~153 MB needed).

typedef __bf16 bh_t;
typedef __bf16 bfx4 __attribute__((ext_vector_type(4)));
typedef __bf16 bfx8 __attribute__((ext_vector_type(8)));
typedef float  fx4  __attribute__((ext_vector_type(4)));

#define CDIM 768
#define TSEQ 1024
#define NHEAD 12
#define HDIM 64
#define NLAYER 12
#define MROWS 4096          // B*T
#define VOCAB 50257
#define VPAD  50304         // 393 * 128

__device__ __forceinline__ void gload_lds16(const void* g, void* l) {
  __builtin_amdgcn_global_load_lds(
      (const __attribute__((address_space(1))) void*)g,
      (__attribute__((address_space(3))) void*)l, 16, 0, 0);
}

__device__ __forceinline__ fx4 mfma16(bfx8 a, bfx8 b, fx4 c) {
  return __builtin_amdgcn_mfma_f32_16x16x32_bf16(a, b, c, 0, 0, 0);
}

// ---------------------------------------------------------------------------
// GEMM: C[M,N] = A[M,K] @ B^T[N,K]  (+bias, +gelu, +residual), out f32 or bf16
// m97 structure: 128x128 tile, BK=32, 4 waves (2x2), global_load_lds staging.
// grid = (M/128, ceil(N/128)); K % 32 == 0; M % 128 == 0.
// flags: 1=bias, 2=residual(f32, ld=N), 4=gelu, 8=out bf16
// ---------------------------------------------------------------------------
__global__ __launch_bounds__(256, 3) void gemm_bt(
    const bh_t* __restrict__ A, const bh_t* __restrict__ B,
    const float* __restrict__ bias, const float* __restrict__ resid,
    void* __restrict__ outp, int M, int N, int K, int flags)
{
  __shared__ bh_t As[4][128][8];   // [k-block][row][8 contiguous k]
  __shared__ bh_t Bs[4][128][8];
  const int tid  = threadIdx.x;
  const int wave = tid >> 6, lane = tid & 63;
  const int g = lane >> 4, r16 = lane & 15;
  const int m0 = blockIdx.x * 128, n0 = blockIdx.y * 128;
  const int wm = (wave >> 1) * 64, wn = (wave & 1) * 64;

  fx4 acc[4][4] = {};

  const int c0 = tid, c1 = tid + 256;
  const int row0 = c0 & 127, kb0 = c0 >> 7;
  const int row1 = c1 & 127, kb1 = c1 >> 7;
  bh_t* AsF = &As[0][0][0];
  bh_t* BsF = &Bs[0][0][0];

  for (int k0 = 0; k0 < K; k0 += 32) {
    gload_lds16(A + (size_t)(m0 + row0) * K + k0 + kb0 * 8, AsF + (size_t)(wave * 64) * 8);
    gload_lds16(A + (size_t)(m0 + row1) * K + k0 + kb1 * 8, AsF + (size_t)(256 + wave * 64) * 8);
    gload_lds16(B + (size_t)(n0 + row0) * K + k0 + kb0 * 8, BsF + (size_t)(wave * 64) * 8);
    gload_lds16(B + (size_t)(n0 + row1) * K + k0 + kb1 * 8, BsF + (size_t)(256 + wave * 64) * 8);
    __syncthreads();   // drains vmcnt -> LDS tiles ready
    bfx8 af[4], bfr[4];
    #pragma unroll
    for (int mi = 0; mi < 4; ++mi) af[mi]  = *(const bfx8*)&As[g][wm + mi * 16 + r16][0];
    #pragma unroll
    for (int ni = 0; ni < 4; ++ni) bfr[ni] = *(const bfx8*)&Bs[g][wn + ni * 16 + r16][0];
    #pragma unroll
    for (int mi = 0; mi < 4; ++mi)
      #pragma unroll
      for (int ni = 0; ni < 4; ++ni)
        acc[mi][ni] = mfma16(af[mi], bfr[ni], acc[mi][ni]);
    __syncthreads();   // all reads done before next stage overwrites
  }

  const bool hasBias = flags & 1, hasRes = flags & 2;
  const bool doGelu  = flags & 4, outBf  = flags & 8;
  float* outF = (float*)outp;
  bh_t*  outB = (bh_t*)outp;
  #pragma unroll
  for (int mi = 0; mi < 4; ++mi) {
    #pragma unroll
    for (int ni = 0; ni < 4; ++ni) {
      const int col = n0 + wn + ni * 16 + r16;
      if (col >= N) continue;
      const int rowb = m0 + wm + mi * 16 + 4 * g;
      const float bv = hasBias ? bias[col] : 0.0f;
      #pragma unroll
      for (int rr = 0; rr < 4; ++rr) {
        const size_t idx = (size_t)(rowb + rr) * N + col;
        float v = acc[mi][ni][rr] + bv;
        if (doGelu) v = 0.5f * v * (1.0f + erff(v * 0.70710678118654752f));
        if (hasRes) v += resid[idx];
        if (outBf) outB[idx] = (bh_t)v; else outF[idx] = v;
      }
    }
  }
}

// ---------------------------------------------------------------------------
// Flash attention, causal. One wave per (b, h, 16 q-rows). Swapped QK^T so
// softmax state is lane-local per q (q = lane&15); P repacked via per-wave LDS.
// qkv: [B*T][3C] bf16; vT: [B*H*64][T] bf16; out: [B*T][C] bf16.
// ---------------------------------------------------------------------------
__global__ __launch_bounds__(256) void attn_fwd(
    const bh_t* __restrict__ qkv, const bh_t* __restrict__ vT,
    bh_t* __restrict__ outb)
{
  __shared__ bh_t P[4][16][56];    // per-wave P tile, stride 56 (=112B rows)
  const int wave = threadIdx.x >> 6, lane = threadIdx.x & 63;
  const int g = lane >> 4, r16 = lane & 15;
  const int gw = blockIdx.x * 4 + wave;          // 0 .. B*H*64-1
  const int qblk = gw & 63;
  const int bh = gw >> 6;
  const int h = bh % NHEAD, b = bh / NHEAD;
  const int qbase = qblk * 16;
  const int qidx = qbase + r16;

  const bh_t* qp = qkv + (size_t)(b * TSEQ + qbase + r16) * (3 * CDIM) + h * HDIM + 8 * g;
  const bfx8 qf0 = *(const bfx8*)qp;
  const bfx8 qf1 = *(const bfx8*)(qp + 32);

  fx4 o[4] = {};
  float m = -INFINITY, l = 0.0f;
  const int ntiles = qblk / 2 + 1;

  for (int t = 0; t < ntiles; ++t) {
    const int kv0 = t * 32;
    const bh_t* kp = qkv + (size_t)(b * TSEQ + kv0 + r16) * (3 * CDIM) + CDIM + h * HDIM + 8 * g;
    const bfx8 ka0 = *(const bfx8*)kp;
    const bfx8 ka1 = *(const bfx8*)(kp + 32);
    const bfx8 kb0 = *(const bfx8*)(kp + 16 * (3 * CDIM));
    const bfx8 kb1 = *(const bfx8*)(kp + 16 * (3 * CDIM) + 32);
    fx4 s0 = {}, s1 = {};
    s0 = mfma16(ka0, qf0, s0); s0 = mfma16(ka1, qf1, s0);   // S^T: [kv][q]
    s1 = mfma16(kb0, qf0, s1); s1 = mfma16(kb1, qf1, s1);

    float mx = -INFINITY;
    float sv0[4], sv1[4];
    #pragma unroll
    for (int rr = 0; rr < 4; ++rr) {
      const int kva = kv0 + 4 * g + rr;
      const int kvb = kva + 16;
      sv0[rr] = (kva <= qidx) ? s0[rr] * 0.125f : -INFINITY;
      sv1[rr] = (kvb <= qidx) ? s1[rr] * 0.125f : -INFINITY;
      mx = fmaxf(mx, fmaxf(sv0[rr], sv1[rr]));
    }
    mx = fmaxf(mx, __shfl_xor(mx, 16));
    mx = fmaxf(mx, __shfl_xor(mx, 32));
    const float mnew = fmaxf(m, mx);
    const float corr = __expf(m - mnew);     // m=-inf first tile -> 0

    float ps = 0.0f;
    float pv0[4], pv1[4];
    #pragma unroll
    for (int rr = 0; rr < 4; ++rr) {
      pv0[rr] = __expf(sv0[rr] - mnew);
      pv1[rr] = __expf(sv1[rr] - mnew);
      ps += pv0[rr] + pv1[rr];
    }
    ps += __shfl_xor(ps, 16);
    ps += __shfl_xor(ps, 32);
    l = l * corr + ps;
    m = mnew;

    #pragma unroll
    for (int rr = 0; rr < 4; ++rr) {
      const float cr = __shfl(corr, 4 * g + rr);   // O's q-row = 4g+rr
      o[0][rr] *= cr; o[1][rr] *= cr; o[2][rr] *= cr; o[3][rr] *= cr;
    }

    bfx4 w0, w1;
    #pragma unroll
    for (int rr = 0; rr < 4; ++rr) { w0[rr] = (bh_t)pv0[rr]; w1[rr] = (bh_t)pv1[rr]; }
    *(bfx4*)&P[wave][r16][4 * g]      = w0;    // kv = 4g..4g+3
    *(bfx4*)&P[wave][r16][16 + 4 * g] = w1;    // kv = 16+4g..
    __builtin_amdgcn_wave_barrier();
    const bfx8 pf = *(const bfx8*)&P[wave][r16][8 * g];   // A-frag: q=lane&15, kv=8g..8g+7

    #pragma unroll
    for (int fi = 0; fi < 4; ++fi) {
      const bh_t* vp = vT + (size_t)(bh * HDIM + fi * 16 + r16) * TSEQ + kv0 + 8 * g;
      const bfx8 vf = *(const bfx8*)vp;
      o[fi] = mfma16(pf, vf, o[fi]);
    }
  }

  #pragma unroll
  for (int rr = 0; rr < 4; ++rr) {
    const float lr = __shfl(l, 4 * g + rr);
    const float inv = 1.0f / lr;
    const int trow = b * TSEQ + qbase + 4 * g + rr;
    #pragma unroll
    for (int fi = 0; fi < 4; ++fi)
      outb[(size_t)trow * CDIM + h * HDIM + fi * 16 + r16] = (bh_t)(o[fi][rr] * inv);
  }
}

// ---------------------------------------------------------------------------
// LayerNorm: f32 in -> bf16 out. One wave per row (C=768, 12 elems/lane).
// ---------------------------------------------------------------------------
__global__ __launch_bounds__(256) void ln_fwd(
    const float* __restrict__ x, const float* __restrict__ w,
    const float* __restrict__ bb, bh_t* __restrict__ out)
{
  const int wave = threadIdx.x >> 6, lane = threadIdx.x & 63;
  const int row = blockIdx.x * 4 + wave;
  const float* xr = x + (size_t)row * CDIM;
  const int off = lane * 4;
  const float4 v0 = *(const float4*)(xr + off);
  const float4 v1 = *(const float4*)(xr + 256 + off);
  const float4 v2 = *(const float4*)(xr + 512 + off);
  float s  = v0.x + v0.y + v0.z + v0.w + v1.x + v1.y + v1.z + v1.w
           + v2.x + v2.y + v2.z + v2.w;
  float ss = v0.x*v0.x + v0.y*v0.y + v0.z*v0.z + v0.w*v0.w
           + v1.x*v1.x + v1.y*v1.y + v1.z*v1.z + v1.w*v1.w
           + v2.x*v2.x + v2.y*v2.y + v2.z*v2.z + v2.w*v2.w;
  #pragma unroll
  for (int d = 1; d < 64; d <<= 1) { s += __shfl_xor(s, d); ss += __shfl_xor(ss, d); }
  const float mean = s * (1.0f / 768.0f);
  const float inv = rsqrtf(ss * (1.0f / 768.0f) - mean * mean + 1e-5f);
  bh_t* orow = out + (size_t)row * CDIM;

  const float4 w0 = *(const float4*)(w + off),  b0 = *(const float4*)(bb + off);
  const float4 w1 = *(const float4*)(w + 256 + off), b1 = *(const float4*)(bb + 256 + off);
  const float4 w2 = *(const float4*)(w + 512 + off), b2 = *(const float4*)(bb + 512 + off);
  bfx4 o;
  o[0] = (bh_t)((v0.x - mean) * inv * w0.x + b0.x);
  o[1] = (bh_t)((v0.y - mean) * inv * w0.y + b0.y);
  o[2] = (bh_t)((v0.z - mean) * inv * w0.z + b0.z);
  o[3] = (bh_t)((v0.w - mean) * inv * w0.w + b0.w);
  *(bfx4*)(orow + off) = o;
  o[0] = (bh_t)((v1.x - mean) * inv * w1.x + b1.x);
  o[1] = (bh_t)((v1.y - mean) * inv * w1.y + b1.y);
  o[2] = (bh_t)((v1.z - mean) * inv * w1.z + b1.z);
  o[3] = (bh_t)((v1.w - mean) * inv * w1.w + b1.w);
  *(bfx4*)(orow + 256 + off) = o;
  o[0] = (bh_t)((v2.x - mean) * inv * w2.x + b2.x);
  o[1] = (bh_t)((v2.y - mean) * inv * w2.y + b2.y);
  o[2] = (bh_t)((v2.z - mean) * inv * w2.z + b2.z);
  o[3] = (bh_t)((v2.w - mean) * inv * w2.w + b2.w);
  *(bfx4*)(orow + 512 + off) = o;
}

// ---------------------------------------------------------------------------
__global__ void embed_k(const int* __restrict__ ids, const float* __restrict__ tok,
                        const float* __restrict__ pos, float* __restrict__ x)
{
  const int bt = blockIdx.x;
  const int t = bt & (TSEQ - 1);
  const int id = ids[bt];
  const float* tr = tok + (size_t)id * CDIM;
  const float* pr = pos + (size_t)t * CDIM;
  float* xr = x + (size_t)bt * CDIM;
  for (int j = threadIdx.x; j < CDIM; j += 256) xr[j] = tr[j] + pr[j];
}

// transpose + f32->bf16: in [L][R][Cn] -> out [L][Cn][R]
__global__ void tconv(const float* __restrict__ in, bh_t* __restrict__ out, int R, int Cn)
{
  __shared__ float tile[32][33];
  const size_t msz = (size_t)R * Cn;
  in  += msz * blockIdx.z;
  out += msz * blockIdx.z;
  const int tx = threadIdx.x & 31, ty = threadIdx.x >> 5;
  const int c0 = blockIdx.x * 32, r0 = blockIdx.y * 32;
  #pragma unroll
  for (int i = 0; i < 32; i += 8)
    tile[ty + i][tx] = in[(size_t)(r0 + ty + i) * Cn + c0 + tx];
  __syncthreads();
  #pragma unroll
  for (int i = 0; i < 32; i += 8)
    out[(size_t)(c0 + ty + i) * R + r0 + tx] = (bh_t)tile[tx][ty + i];
}

// tok_emb f32 [V][C] -> bf16 [VPAD][C], zero-padded rows
__global__ void embconv(const float* __restrict__ in, bh_t* __restrict__ out)
{
  const size_t i4 = ((size_t)blockIdx.x * 256 + threadIdx.x) * 4;
  const size_t vlim = (size_t)VOCAB * CDIM;
  float4 f = make_float4(0.f, 0.f, 0.f, 0.f);
  if (i4 < vlim) f = *(const float4*)(in + i4);
  bfx4 o;
  o[0] = (bh_t)f.x; o[1] = (bh_t)f.y; o[2] = (bh_t)f.z; o[3] = (bh_t)f.w;
  *(bfx4*)(out + i4) = o;
}

// V slice of qkv -> vT[bh*64 + d][t]
__global__ void vtrans(const bh_t* __restrict__ qkv, bh_t* __restrict__ vT)
{
  __shared__ bh_t tile[32][34];
  const int bh = blockIdx.z;
  const int b = bh / NHEAD, h = bh % NHEAD;
  const int d0 = blockIdx.x * 32, t0 = blockIdx.y * 32;
  const int tx = threadIdx.x & 31, ty = threadIdx.x >> 5;
  #pragma unroll
  for (int i = 0; i < 32; i += 8)
    tile[ty + i][tx] = qkv[(size_t)(b * TSEQ + t0 + ty + i) * (3 * CDIM) + 2 * CDIM + h * HDIM + d0 + tx];
  __syncthreads();
  #pragma unroll
  for (int i = 0; i < 32; i += 8)
    vT[(size_t)(bh * HDIM + d0 + ty + i) * TSEQ + t0 + tx] = tile[tx][ty + i];
}

// ---------------------------------------------------------------------------
extern "C" void kernel_launch(void* const* d_in, const int* in_sizes, int n_in,
                              void* d_out, int out_size, void* d_ws, size_t ws_size,
                              hipStream_t stream)
{
  (void)in_sizes; (void)n_in; (void)out_size; (void)ws_size;
  const int*   ids    = (const int*)d_in[0];
  const float* tok    = (const float*)d_in[1];
  const float* pos    = (const float*)d_in[2];
  const float* qkv_w  = (const float*)d_in[3];
  const float* qkv_b  = (const float*)d_in[4];
  const float* proj_w = (const float*)d_in[5];
  const float* proj_b = (const float*)d_in[6];
  const float* ln1_w  = (const float*)d_in[7];
  const float* ln1_b  = (const float*)d_in[8];
  const float* ln2_w  = (const float*)d_in[9];
  const float* ln2_b  = (const float*)d_in[10];
  const float* fc1_w  = (const float*)d_in[11];
  const float* fc1_b  = (const float*)d_in[12];
  const float* fc2_w  = (const float*)d_in[13];
  const float* fc2_b  = (const float*)d_in[14];
  const float* lnf_w  = (const float*)d_in[15];
  const float* lnf_b  = (const float*)d_in[16];

  // ---- scratch in ws (activations + embT), ~153 MB
  char* wp = (char*)d_ws;
  auto carve = [&](size_t bytes) { char* p = wp; wp += (bytes + 255) & ~(size_t)255; return p; };
  float* x     = (float*)carve((size_t)MROWS * CDIM * 4);
  bh_t*  hbuf  = (bh_t*)carve((size_t)MROWS * CDIM * 2);
  bh_t*  qkvb  = (bh_t*)carve((size_t)MROWS * 3 * CDIM * 2);
  bh_t*  vT    = (bh_t*)carve((size_t)48 * HDIM * TSEQ * 2);
  bh_t*  attno = (bh_t*)carve((size_t)MROWS * CDIM * 2);
  bh_t*  mlp1  = (bh_t*)carve((size_t)MROWS * 3072 * 2);
  bh_t*  embT  = (bh_t*)carve((size_t)VPAD * CDIM * 2);

  // ---- bf16 weight transposes carved from d_out (dead before lm_head writes)
  char* op = (char*)d_out;
  auto carveO = [&](size_t bytes) { char* p = op; op += (bytes + 255) & ~(size_t)255; return p; };
  bh_t* qkvwT = (bh_t*)carveO((size_t)NLAYER * 3 * CDIM * CDIM * 2);
  bh_t* projwT = (bh_t*)carveO((size_t)NLAYER * CDIM * CDIM * 2);
  bh_t* fc1wT = (bh_t*)carveO((size_t)NLAYER * 3072 * CDIM * 2);
  bh_t* fc2wT = (bh_t*)carveO((size_t)NLAYER * CDIM * 3072 * 2);

  tconv<<<dim3(2304 / 32, 768 / 32, NLAYER), 256, 0, stream>>>(qkv_w, qkvwT, 768, 2304);
  tconv<<<dim3(768 / 32, 768 / 32, NLAYER), 256, 0, stream>>>(proj_w, projwT, 768, 768);
  tconv<<<dim3(3072 / 32, 768 / 32, NLAYER), 256, 0, stream>>>(fc1_w, fc1wT, 768, 3072);
  tconv<<<dim3(768 / 32, 3072 / 32, NLAYER), 256, 0, stream>>>(fc2_w, fc2wT, 3072, 768);
  embconv<<<(VPAD * CDIM / 4) / 256, 256, 0, stream>>>(tok, embT);
  embed_k<<<MROWS, 256, 0, stream>>>(ids, tok, pos, x);

  for (int l = 0; l < NLAYER; ++l) {
    ln_fwd<<<MROWS / 4, 256, 0, stream>>>(x, ln1_w + l * CDIM, ln1_b + l * CDIM, hbuf);
    gemm_bt<<<dim3(32, 18), 256, 0, stream>>>(hbuf, qkvwT + (size_t)l * 3 * CDIM * CDIM,
        qkv_b + l * 3 * CDIM, nullptr, qkvb, MROWS, 3 * CDIM, CDIM, 1 | 8);
    vtrans<<<dim3(2, 32, 48), 256, 0, stream>>>(qkvb, vT);
    attn_fwd<<<768, 256, 0, stream>>>(qkvb, vT, attno);
    gemm_bt<<<dim3(32, 6), 256, 0, stream>>>(attno, projwT + (size_t)l * CDIM * CDIM,
        proj_b + l * CDIM, x, x, MROWS, CDIM, CDIM, 1 | 2);
    ln_fwd<<<MROWS / 4, 256, 0, stream>>>(x, ln2_w + l * CDIM, ln2_b + l * CDIM, hbuf);
    gemm_bt<<<dim3(32, 24), 256, 0, stream>>>(hbuf, fc1wT + (size_t)l * 3072 * CDIM,
        fc1_b + l * 3072, nullptr, mlp1, MROWS, 3072, CDIM, 1 | 4 | 8);
    gemm_bt<<<dim3(32, 6), 256, 0, stream>>>(mlp1, fc2wT + (size_t)l * CDIM * 3072,
        fc2_b + l * CDIM, x, x, MROWS, CDIM, 3072, 1 | 2);
  }
  ln_fwd<<<MROWS / 4, 256, 0, stream>>>(x, lnf_w, lnf_b, hbuf);
  gemm_bt<<<dim3(32, VPAD / 128), 256, 0, stream>>>(hbuf, embT, nullptr, nullptr,
      (float*)d_out, MROWS, VOCAB, CDIM, 0);
}